// Round 9
// baseline (719.388 us; speedup 1.0000x reference)
//
#include <hip/hip_runtime.h>

using u16 = unsigned short;
typedef __attribute__((ext_vector_type(8))) short short8;
typedef __attribute__((ext_vector_type(4))) float f32x4;

#define DEV __device__ __forceinline__

DEV float bf2f(u16 u) { union { unsigned i; float f; } v; v.i = (unsigned)u << 16; return v.f; }
DEV u16 f2bf(float f) {
  union { float f; unsigned i; } v; v.f = f;
  return (u16)((v.i + 0x7fffu + ((v.i >> 16) & 1u)) >> 16);
}
// async global->LDS, 16B per lane. dst is wave-uniform base; HW adds lane*16.
DEV void async16(void* lds, const void* g) {
  __builtin_amdgcn_global_load_lds((const __attribute__((address_space(1))) void*)g,
                                   (__attribute__((address_space(3))) void*)lds, 16, 0, 0);
}

// ---------------- fp32 -> bf16 convert ----------------
__global__ __launch_bounds__(256) void cvt_bf16(const float* __restrict__ in,
                                                u16* __restrict__ out, int n) {
  int i = (blockIdx.x * 256 + threadIdx.x) * 8;
  if (i >= n) return;
  const float4* p = (const float4*)(in + i);
  float4 a = p[0], b = p[1];
  short8 o;
  o[0] = (short)f2bf(a.x); o[1] = (short)f2bf(a.y);
  o[2] = (short)f2bf(a.z); o[3] = (short)f2bf(a.w);
  o[4] = (short)f2bf(b.x); o[5] = (short)f2bf(b.y);
  o[6] = (short)f2bf(b.z); o[7] = (short)f2bf(b.w);
  *(short8*)(out + i) = o;
}

// ---------------- GEMM: C[M=4096][N=2048] = A[4096][2048] * Bw[2048][2048]^T ----
// m97 structure: 128x128 tile, BK=32, 4 waves each 64x64, global_load_lds w=16.
template <bool BF16OUT>
DEV void gemm_body(const u16* __restrict__ A, const u16* __restrict__ Bw,
                   void* __restrict__ C, u16* As, u16* Bs) {
  constexpr int KD = 2048, N = 2048;
  const int tid = threadIdx.x, lane = tid & 63, w = tid >> 6;
  const int wm = (w >> 1) * 64, wn = (w & 1) * 64;
  const int lr = lane & 15, lk = lane >> 4;
  const size_t m0 = (size_t)blockIdx.y * 128, n0 = (size_t)blockIdx.x * 128;

  f32x4 acc[4][4];
#pragma unroll
  for (int i = 0; i < 4; ++i)
#pragma unroll
    for (int j = 0; j < 4; ++j) acc[i][j] = (f32x4){0.f, 0.f, 0.f, 0.f};

  const int bo0 = tid * 16;
  for (int kt = 0; kt < KD; kt += 32) {
#pragma unroll
    for (int i = 0; i < 2; ++i) {
      int bo = i * 4096 + bo0;
      int row = bo >> 6, cb = bo & 63;  // tile row / byte-in-row (64B rows)
      async16((char*)As + i * 4096 + w * 1024,
              (const char*)A + ((m0 + row) * KD + kt) * 2 + cb);
    }
#pragma unroll
    for (int i = 0; i < 2; ++i) {
      int bo = i * 4096 + bo0;
      int row = bo >> 6, cb = bo & 63;
      async16((char*)Bs + i * 4096 + w * 1024,
              (const char*)Bw + ((n0 + row) * KD + kt) * 2 + cb);
    }
    __syncthreads();  // compiler drains vmcnt before s_barrier
    short8 a[4], b[4];
#pragma unroll
    for (int mi = 0; mi < 4; ++mi)
      a[mi] = *(const short8*)(As + (wm + mi * 16 + lr) * 32 + lk * 8);
#pragma unroll
    for (int ni = 0; ni < 4; ++ni)
      b[ni] = *(const short8*)(Bs + (wn + ni * 16 + lr) * 32 + lk * 8);
#pragma unroll
    for (int mi = 0; mi < 4; ++mi)
#pragma unroll
      for (int ni = 0; ni < 4; ++ni)
        acc[mi][ni] =
            __builtin_amdgcn_mfma_f32_16x16x32_bf16(a[mi], b[ni], acc[mi][ni], 0, 0, 0);
    __syncthreads();
  }
  // D layout: col = lane&15, row = (lane>>4)*4 + reg
#pragma unroll
  for (int mi = 0; mi < 4; ++mi)
#pragma unroll
    for (int ni = 0; ni < 4; ++ni)
#pragma unroll
      for (int r = 0; r < 4; ++r) {
        size_t row = m0 + wm + mi * 16 + lk * 4 + r;
        size_t col = n0 + wn + ni * 16 + lr;
        if constexpr (BF16OUT)
          ((u16*)C)[row * N + col] = f2bf(acc[mi][ni][r]);
        else
          ((float*)C)[row * N + col] = acc[mi][ni][r];
      }
}

__global__ __launch_bounds__(256) void gemm_qkv(
    const u16* __restrict__ X, const u16* __restrict__ Wq, const u16* __restrict__ Wk,
    const u16* __restrict__ Wv, u16* __restrict__ Qo, u16* __restrict__ Ko,
    u16* __restrict__ Vo) {
  __shared__ u16 As[128 * 32], Bs[128 * 32];
  const u16* W = blockIdx.z == 0 ? Wq : (blockIdx.z == 1 ? Wk : Wv);
  u16* C = blockIdx.z == 0 ? Qo : (blockIdx.z == 1 ? Ko : Vo);
  gemm_body<true>(X, W, C, As, Bs);
}

__global__ __launch_bounds__(256) void gemm_out(const u16* __restrict__ A,
                                                const u16* __restrict__ W,
                                                float* __restrict__ C) {
  __shared__ u16 As[128 * 32], Bs[128 * 32];
  gemm_body<false>(A, W, C, As, Bs);
}

// ---------------- RMSNorm + RoPE (in-place on bf16 q,k) ----------------
// One wave per (b,t,h) row of 128. q additionally pre-scaled by (1/sqrt(D))*log2(e)
// so the attention kernel works directly in the exp2 domain.
__global__ __launch_bounds__(256) void rmsrope(u16* __restrict__ q, u16* __restrict__ k,
                                               const float* __restrict__ cosb,
                                               const float* __restrict__ sinb) {
  int gw = blockIdx.x * 4 + (threadIdx.x >> 6);
  int lane = threadIdx.x & 63;
  u16* base = q;
  float pre = 0.088388347648318447f * 1.4426950408889634f;
  if (gw >= 65536) { base = k; gw -= 65536; pre = 1.0f; }
  int bt = gw >> 4, h = gw & 15, t = bt & 2047;
  u16* p = base + (size_t)bt * 2048 + h * 128;
  float x1 = bf2f(p[lane]), x2 = bf2f(p[lane + 64]);
  float ss = x1 * x1 + x2 * x2;
#pragma unroll
  for (int m = 1; m < 64; m <<= 1) ss += __shfl_xor(ss, m, 64);
  float rn = rsqrtf(ss * (1.0f / 128.0f) + 1.1920929e-7f) * pre;
  float c = cosb[t * 64 + lane], s = sinb[t * 64 + lane];
  float y1 = (x1 * c + x2 * s) * rn;
  float y2 = (x2 * c - x1 * s) * rn;  // -x1*sin + x2*cos
  p[lane] = f2bf(y1);
  p[lane + 64] = f2bf(y2);
}

// ---------------- V transpose: v[b][t][h][d] -> vt[(b,h)][d][t] ----------------
__global__ __launch_bounds__(256) void transpose_v(const u16* __restrict__ v,
                                                   u16* __restrict__ vt) {
  __shared__ u16 tile[64][72];
  int bh = blockIdx.z, b = bh >> 4, h = bh & 15;
  int t0 = blockIdx.x * 64, d0 = blockIdx.y * 64;
  int tid = threadIdx.x;
  int rr = tid >> 3, ch = tid & 7;
#pragma unroll
  for (int p = 0; p < 2; ++p) {
    int t = rr + p * 32;
    const u16* src = v + ((size_t)(b * 2048 + t0 + t) * 2048 + h * 128 + d0 + ch * 8);
    *(short8*)&tile[t][ch * 8] = *(const short8*)src;
  }
  __syncthreads();
#pragma unroll
  for (int p = 0; p < 2; ++p) {
    int d = rr + p * 32;
    int oc = ch * 8;
    short8 val;
#pragma unroll
    for (int j = 0; j < 8; ++j) val[j] = (short)tile[oc + j][d];
    *(short8*)(vt + ((size_t)(bh * 128 + d0 + d) * 2048 + t0 + oc)) = val;
  }
}

// ---------------- causal flash attention (merged-pair sweep) ----------------
// grid (32 bh, 16 pairs): x = bh so the 16 blocks sharing a (b,h)'s K/V have
// linear ids == bh (mod 8) -> same XCD under round-robin dispatch -> K/V (1 MB)
// re-reads become that XCD's L2 hits (4 bh x 1 MB ~= 4 MB L2).
// Block p owns q-tiles {p, 31-p}; ONE KV sweep of nt_far tiles serves both
// (prefix(near) is a subset of prefix(far)) -> staged tiles 17 -> 12.5 avg.
// K staged [128][128], Vt staged [128][128], XOR-swizzled via pre-swizzled
// global source (rule 21); P per-wave [16][128] with element-XOR swizzle (G4).
// Q pre-scaled by 1/sqrt(D)*log2e -> S already in exp2 domain.
DEV void attn_step(const short8* aq, float* mrow, float* lrow, f32x4* o,
                   const u16* Ks, const u16* Vs, u16* pw,
                   int lr, int lk, bool diag, int nlim, int qw, int kv0) {
  f32x4 s[8];
#pragma unroll
  for (int n = 0; n < 8; ++n) {
    s[n] = (f32x4){-__builtin_inff(), -__builtin_inff(), -__builtin_inff(),
                   -__builtin_inff()};
    if (!diag || n < nlim) {
      f32x4 t = (f32x4){0.f, 0.f, 0.f, 0.f};
#pragma unroll
      for (int kk = 0; kk < 4; ++kk) {
        int row = n * 16 + lr;
        int cb = kk * 64 + lk * 16;
        short8 bk =
            *(const short8*)((const char*)Ks + row * 256 + (cb ^ ((row & 7) << 4)));
        t = __builtin_amdgcn_mfma_f32_16x16x32_bf16(aq[kk], bk, t, 0, 0, 0);
      }
      s[n] = t;
    }
  }
  if (diag) {  // causal mask within live frags
#pragma unroll
    for (int n = 0; n < 8; ++n)
#pragma unroll
      for (int r = 0; r < 4; ++r) {
        int col = kv0 + n * 16 + lr;
        int row = qw + lk * 4 + r;
        if (col > row) s[n][r] = -__builtin_inff();
      }
  }
  float al[4];
#pragma unroll
  for (int r = 0; r < 4; ++r) {
    float mx = s[0][r];
#pragma unroll
    for (int n = 1; n < 8; ++n) mx = fmaxf(mx, s[n][r]);
    mx = fmaxf(mx, __shfl_xor(mx, 1, 64));
    mx = fmaxf(mx, __shfl_xor(mx, 2, 64));
    mx = fmaxf(mx, __shfl_xor(mx, 4, 64));
    mx = fmaxf(mx, __shfl_xor(mx, 8, 64));
    float mn = fmaxf(mrow[r], mx);
    al[r] = exp2f(mrow[r] - mn);
    mrow[r] = mn;
  }
  float rs[4] = {0.f, 0.f, 0.f, 0.f};
#pragma unroll
  for (int n = 0; n < 8; ++n)
#pragma unroll
    for (int r = 0; r < 4; ++r) {
      float pv = exp2f(s[n][r] - mrow[r]);
      s[n][r] = pv;
      rs[r] += pv;
    }
#pragma unroll
  for (int r = 0; r < 4; ++r) {
    float t = rs[r];
    t += __shfl_xor(t, 1, 64); t += __shfl_xor(t, 2, 64);
    t += __shfl_xor(t, 4, 64); t += __shfl_xor(t, 8, 64);
    lrow[r] = lrow[r] * al[r] + t;
  }
#pragma unroll
  for (int nd = 0; nd < 8; ++nd)
#pragma unroll
    for (int r = 0; r < 4; ++r) o[nd][r] *= al[r];

  // P -> per-wave LDS (D-layout write, A-layout read; XOR swizzle both sides)
#pragma unroll
  for (int n = 0; n < 8; ++n)
#pragma unroll
    for (int r = 0; r < 4; ++r) {
      int prow = lk * 4 + r;
      pw[prow * 128 + ((n * 16 + lr) ^ ((prow & 7) << 3))] = f2bf(s[n][r]);
    }

#pragma unroll
  for (int kk = 0; kk < 4; ++kk) {
    short8 pa = *(const short8*)(pw + lr * 128 + ((kk * 32 + lk * 8) ^ ((lr & 7) << 3)));
#pragma unroll
    for (int nd = 0; nd < 8; ++nd) {
      int dr = nd * 16 + lr;
      int cb = kk * 64 + lk * 16;
      short8 bv = *(const short8*)((const char*)Vs + dr * 256 + (cb ^ ((dr & 7) << 4)));
      o[nd] = __builtin_amdgcn_mfma_f32_16x16x32_bf16(pa, bv, o[nd], 0, 0, 0);
    }
  }
}

__global__ __launch_bounds__(256, 2) void attn_fwd(const u16* __restrict__ Q,
                                                   const u16* __restrict__ K,
                                                   const u16* __restrict__ Vt,
                                                   u16* __restrict__ O) {
  __shared__ u16 Ks[128 * 128];
  __shared__ u16 Vs[128 * 128];
  __shared__ u16 Ps[4][16 * 128];
  const int tid = threadIdx.x, lane = tid & 63, w = tid >> 6;
  const int lr = lane & 15, lk = lane >> 4;
  const int bh = blockIdx.x, b = bh >> 4, h = bh & 15;
  const int p = blockIdx.y;

  const int qt_f = 31 - p, qt_n = p;
  const int qw_f = qt_f * 64 + w * 16, qw_n = qt_n * 64 + w * 16;
  const int nt_f = (qt_f >> 1) + 1, nt_n = (qt_n >> 1) + 1;
  const int nlim_f = (qt_f & 1) ? 8 : 4, nlim_n = (qt_n & 1) ? 8 : 4;

  const char* kbase = (const char*)(K + ((size_t)b * 2048) * 2048 + h * 128);
  const char* vbase = (const char*)(Vt + (size_t)bh * 128 * 2048);
  const int bo0 = tid * 16;
  u16* pw = Ps[w];

  // Q fragments for both q-tiles (A-frag: row=lane&15, k=(lane>>4)*8+j)
  short8 aq_f[4], aq_n[4];
  {
    const u16* qf = Q + ((size_t)(b * 2048 + qw_f + lr)) * 2048 + h * 128;
    const u16* qn = Q + ((size_t)(b * 2048 + qw_n + lr)) * 2048 + h * 128;
#pragma unroll
    for (int kk = 0; kk < 4; ++kk) {
      aq_f[kk] = *(const short8*)(qf + kk * 32 + lk * 8);
      aq_n[kk] = *(const short8*)(qn + kk * 32 + lk * 8);
    }
  }

  float m_f[4], l_f[4], m_n[4], l_n[4];
  f32x4 o_f[8], o_n[8];
#pragma unroll
  for (int r = 0; r < 4; ++r) {
    m_f[r] = -__builtin_inff(); l_f[r] = 0.f;
    m_n[r] = -__builtin_inff(); l_n[r] = 0.f;
  }
#pragma unroll
  for (int nd = 0; nd < 8; ++nd) {
    o_f[nd] = (f32x4){0.f, 0.f, 0.f, 0.f};
    o_n[nd] = (f32x4){0.f, 0.f, 0.f, 0.f};
  }

  for (int kt = 0; kt < nt_f; ++kt) {
    const int kv0 = kt * 128;
#pragma unroll
    for (int i = 0; i < 8; ++i) {  // K tile: 128 rows x 256B
      int bo = i * 4096 + bo0;
      int r = bo >> 8, cb = bo & 255;
      async16((char*)Ks + i * 4096 + w * 1024,
              kbase + (size_t)(kv0 + r) * 4096 + (cb ^ ((r & 7) << 4)));
    }
#pragma unroll
    for (int i = 0; i < 8; ++i) {  // Vt tile: 128 d-rows x 256B
      int bo = i * 4096 + bo0;
      int d = bo >> 8, cb = bo & 255;
      async16((char*)Vs + i * 4096 + w * 1024,
              vbase + (size_t)d * 4096 + (size_t)kv0 * 2 + (cb ^ ((d & 7) << 4)));
    }
    __syncthreads();

    attn_step(aq_f, m_f, l_f, o_f, Ks, Vs, pw, lr, lk, kt == nt_f - 1, nlim_f,
              qw_f, kv0);
    if (kt < nt_n)
      attn_step(aq_n, m_n, l_n, o_n, Ks, Vs, pw, lr, lk, kt == nt_n - 1, nlim_n,
                qw_n, kv0);
    __syncthreads();
  }

  u16* of = O + ((size_t)(b * 2048 + qw_f + lk * 4)) * 2048 + h * 128;
  u16* on = O + ((size_t)(b * 2048 + qw_n + lk * 4)) * 2048 + h * 128;
#pragma unroll
  for (int r = 0; r < 4; ++r) {
    float invf = 1.0f / l_f[r], invn = 1.0f / l_n[r];
#pragma unroll
    for (int nd = 0; nd < 8; ++nd) {
      of[(size_t)r * 2048 + nd * 16 + lr] = f2bf(o_f[nd][r] * invf);
      on[(size_t)r * 2048 + nd * 16 + lr] = f2bf(o_n[nd][r] * invn);
    }
  }
}

extern "C" void kernel_launch(void* const* d_in, const int* in_sizes, int n_in,
                              void* d_out, int out_size, void* d_ws, size_t ws_size,
                              hipStream_t stream) {
  const float* x = (const float*)d_in[0];
  const float* cosb = (const float*)d_in[1];
  const float* sinb = (const float*)d_in[2];
  const float* Wq = (const float*)d_in[3];
  const float* Wk = (const float*)d_in[4];
  const float* Wv = (const float*)d_in[5];
  const float* Wo = (const float*)d_in[6];
  float* out = (float*)d_out;
  char* ws = (char*)d_ws;

  const size_t XB = (size_t)4096 * 2048 * 2;  // 16 MiB (bf16 activations)
  const size_t WB = (size_t)2048 * 2048 * 2;  // 8 MiB (bf16 weights)
  u16* xb  = (u16*)(ws);
  u16* wqb = (u16*)(ws + XB);
  u16* wkb = (u16*)(ws + XB + WB);
  u16* wvb = (u16*)(ws + XB + 2 * WB);
  u16* wob = (u16*)(ws + XB + 3 * WB);
  u16* qb  = (u16*)(ws + XB + 4 * WB);
  u16* kb  = (u16*)(ws + XB + 4 * WB + XB);
  u16* vb  = (u16*)(ws + XB + 4 * WB + 2 * XB);
  u16* vtb = (u16*)(ws + XB + 4 * WB + 3 * XB);
  u16* ob  = (u16*)(ws + XB + 4 * WB + 4 * XB);  // total 128 MiB

  cvt_bf16<<<4096, 256, 0, stream>>>(x, xb, 8388608);
  cvt_bf16<<<2048, 256, 0, stream>>>(Wq, wqb, 4194304);
  cvt_bf16<<<2048, 256, 0, stream>>>(Wk, wkb, 4194304);
  cvt_bf16<<<2048, 256, 0, stream>>>(Wv, wvb, 4194304);
  cvt_bf16<<<2048, 256, 0, stream>>>(Wo, wob, 4194304);
  gemm_qkv<<<dim3(16, 32, 3), 256, 0, stream>>>(xb, wqb, wkb, wvb, qb, kb, vb);
  rmsrope<<<32768, 256, 0, stream>>>(qb, kb, cosb, sinb);
  transpose_v<<<dim3(32, 2, 32), 256, 0, stream>>>(vb, vtb);
  attn_fwd<<<dim3(32, 16), 256, 0, stream>>>(qb, kb, vtb, ob);
  gemm_out<<<dim3(16, 32), 256, 0, stream>>>(ob, wob, out);
}

// Round 11
// 465.438 us; speedup vs baseline: 1.5456x; 1.5456x over previous
//
#include <hip/hip_runtime.h>

using u16 = unsigned short;
typedef __attribute__((ext_vector_type(8))) short short8;
typedef __attribute__((ext_vector_type(4))) float f32x4;

#define DEV __device__ __forceinline__

DEV float bf2f(u16 u) { union { unsigned i; float f; } v; v.i = (unsigned)u << 16; return v.f; }
DEV u16 f2bf(float f) {
  union { float f; unsigned i; } v; v.f = f;
  return (u16)((v.i + 0x7fffu + ((v.i >> 16) & 1u)) >> 16);
}
// async global->LDS, 16B per lane. dst is wave-uniform base; HW adds lane*16.
DEV void async16(void* lds, const void* g) {
  __builtin_amdgcn_global_load_lds((const __attribute__((address_space(1))) void*)g,
                                   (__attribute__((address_space(3))) void*)lds, 16, 0, 0);
}

// ---------------- fp32 -> bf16 convert ----------------
__global__ __launch_bounds__(256) void cvt_bf16(const float* __restrict__ in,
                                                u16* __restrict__ out, int n) {
  int i = (blockIdx.x * 256 + threadIdx.x) * 8;
  if (i >= n) return;
  const float4* p = (const float4*)(in + i);
  float4 a = p[0], b = p[1];
  short8 o;
  o[0] = (short)f2bf(a.x); o[1] = (short)f2bf(a.y);
  o[2] = (short)f2bf(a.z); o[3] = (short)f2bf(a.w);
  o[4] = (short)f2bf(b.x); o[5] = (short)f2bf(b.y);
  o[6] = (short)f2bf(b.z); o[7] = (short)f2bf(b.w);
  *(short8*)(out + i) = o;
}

// ---------------- GEMM: C[M=4096][N=2048] = A[4096][2048] * Bw[2048][2048]^T ----
// m97 structure: 128x128 tile, BK=32, 4 waves each 64x64, global_load_lds w=16.
template <bool BF16OUT>
DEV void gemm_body(const u16* __restrict__ A, const u16* __restrict__ Bw,
                   void* __restrict__ C, u16* As, u16* Bs) {
  constexpr int KD = 2048, N = 2048;
  const int tid = threadIdx.x, lane = tid & 63, w = tid >> 6;
  const int wm = (w >> 1) * 64, wn = (w & 1) * 64;
  const int lr = lane & 15, lk = lane >> 4;
  const size_t m0 = (size_t)blockIdx.y * 128, n0 = (size_t)blockIdx.x * 128;

  f32x4 acc[4][4];
#pragma unroll
  for (int i = 0; i < 4; ++i)
#pragma unroll
    for (int j = 0; j < 4; ++j) acc[i][j] = (f32x4){0.f, 0.f, 0.f, 0.f};

  const int bo0 = tid * 16;
  for (int kt = 0; kt < KD; kt += 32) {
#pragma unroll
    for (int i = 0; i < 2; ++i) {
      int bo = i * 4096 + bo0;
      int row = bo >> 6, cb = bo & 63;  // tile row / byte-in-row (64B rows)
      async16((char*)As + i * 4096 + w * 1024,
              (const char*)A + ((m0 + row) * KD + kt) * 2 + cb);
    }
#pragma unroll
    for (int i = 0; i < 2; ++i) {
      int bo = i * 4096 + bo0;
      int row = bo >> 6, cb = bo & 63;
      async16((char*)Bs + i * 4096 + w * 1024,
              (const char*)Bw + ((n0 + row) * KD + kt) * 2 + cb);
    }
    __syncthreads();  // compiler drains vmcnt before s_barrier
    short8 a[4], b[4];
#pragma unroll
    for (int mi = 0; mi < 4; ++mi)
      a[mi] = *(const short8*)(As + (wm + mi * 16 + lr) * 32 + lk * 8);
#pragma unroll
    for (int ni = 0; ni < 4; ++ni)
      b[ni] = *(const short8*)(Bs + (wn + ni * 16 + lr) * 32 + lk * 8);
#pragma unroll
    for (int mi = 0; mi < 4; ++mi)
#pragma unroll
      for (int ni = 0; ni < 4; ++ni)
        acc[mi][ni] =
            __builtin_amdgcn_mfma_f32_16x16x32_bf16(a[mi], b[ni], acc[mi][ni], 0, 0, 0);
    __syncthreads();
  }
  // D layout: col = lane&15, row = (lane>>4)*4 + reg
#pragma unroll
  for (int mi = 0; mi < 4; ++mi)
#pragma unroll
    for (int ni = 0; ni < 4; ++ni)
#pragma unroll
      for (int r = 0; r < 4; ++r) {
        size_t row = m0 + wm + mi * 16 + lk * 4 + r;
        size_t col = n0 + wn + ni * 16 + lr;
        if constexpr (BF16OUT)
          ((u16*)C)[row * N + col] = f2bf(acc[mi][ni][r]);
        else
          ((float*)C)[row * N + col] = acc[mi][ni][r];
      }
}

__global__ __launch_bounds__(256) void gemm_qkv(
    const u16* __restrict__ X, const u16* __restrict__ Wq, const u16* __restrict__ Wk,
    const u16* __restrict__ Wv, u16* __restrict__ Qo, u16* __restrict__ Ko,
    u16* __restrict__ Vo) {
  __shared__ u16 As[128 * 32], Bs[128 * 32];
  const u16* W = blockIdx.z == 0 ? Wq : (blockIdx.z == 1 ? Wk : Wv);
  u16* C = blockIdx.z == 0 ? Qo : (blockIdx.z == 1 ? Ko : Vo);
  gemm_body<true>(X, W, C, As, Bs);
}

__global__ __launch_bounds__(256) void gemm_out(const u16* __restrict__ A,
                                                const u16* __restrict__ W,
                                                float* __restrict__ C) {
  __shared__ u16 As[128 * 32], Bs[128 * 32];
  gemm_body<false>(A, W, C, As, Bs);
}

// ---------------- RMSNorm + RoPE (in-place on bf16 q,k) ----------------
// One wave per (b,t,h) row of 128. q additionally pre-scaled by (1/sqrt(D))*log2(e)
// so the attention kernel works directly in the exp2 domain.
__global__ __launch_bounds__(256) void rmsrope(u16* __restrict__ q, u16* __restrict__ k,
                                               const float* __restrict__ cosb,
                                               const float* __restrict__ sinb) {
  int gw = blockIdx.x * 4 + (threadIdx.x >> 6);
  int lane = threadIdx.x & 63;
  u16* base = q;
  float pre = 0.088388347648318447f * 1.4426950408889634f;
  if (gw >= 65536) { base = k; gw -= 65536; pre = 1.0f; }
  int bt = gw >> 4, h = gw & 15, t = bt & 2047;
  u16* p = base + (size_t)bt * 2048 + h * 128;
  float x1 = bf2f(p[lane]), x2 = bf2f(p[lane + 64]);
  float ss = x1 * x1 + x2 * x2;
#pragma unroll
  for (int m = 1; m < 64; m <<= 1) ss += __shfl_xor(ss, m, 64);
  float rn = rsqrtf(ss * (1.0f / 128.0f) + 1.1920929e-7f) * pre;
  float c = cosb[t * 64 + lane], s = sinb[t * 64 + lane];
  float y1 = (x1 * c + x2 * s) * rn;
  float y2 = (x2 * c - x1 * s) * rn;  // -x1*sin + x2*cos
  p[lane] = f2bf(y1);
  p[lane + 64] = f2bf(y2);
}

// ---------------- V transpose: v[b][t][h][d] -> vt[(b,h)][d][t] ----------------
__global__ __launch_bounds__(256) void transpose_v(const u16* __restrict__ v,
                                                   u16* __restrict__ vt) {
  __shared__ u16 tile[64][72];
  int bh = blockIdx.z, b = bh >> 4, h = bh & 15;
  int t0 = blockIdx.x * 64, d0 = blockIdx.y * 64;
  int tid = threadIdx.x;
  int rr = tid >> 3, ch = tid & 7;
#pragma unroll
  for (int p = 0; p < 2; ++p) {
    int t = rr + p * 32;
    const u16* src = v + ((size_t)(b * 2048 + t0 + t) * 2048 + h * 128 + d0 + ch * 8);
    *(short8*)&tile[t][ch * 8] = *(const short8*)src;
  }
  __syncthreads();
#pragma unroll
  for (int p = 0; p < 2; ++p) {
    int d = rr + p * 32;
    int oc = ch * 8;
    short8 val;
#pragma unroll
    for (int j = 0; j < 8; ++j) val[j] = (short)tile[oc + j][d];
    *(short8*)(vt + ((size_t)(bh * 128 + d0 + d) * 2048 + t0 + oc)) = val;
  }
}

// ---------------- causal flash attention (round-6 body + co-location + dbuf) ----
// grid (32 bh, 16 pairs): linear id == bh (mod 8) for all 16 blocks sharing a
// (b,h)'s K/V -> same XCD -> KV re-reads become that XCD's L2 hits.
// Block p runs q-tiles {p, 31-p} as two SEQUENTIAL sweeps (single softmax state
// -> no spill; round-9 dual-state spilled 570 MB scratch).
// KV double-buffered (T3/T4 minimum): raw s_barrier + counted vmcnt(16) so the
// 16 just-issued next-tile loads stay in flight across the barrier and stream
// during compute. 16 = async16 per thread per tile (8 K + 8 V).
// K [128][128] & Vt [128][128] XOR-swizzled via pre-swizzled global source
// (rule 21); P per-wave [16][128] element-XOR swizzle (G4).
// Q pre-scaled by 1/sqrt(D)*log2e -> S already in exp2 domain.
__global__ __launch_bounds__(256) void attn_fwd(const u16* __restrict__ Q,
                                                const u16* __restrict__ K,
                                                const u16* __restrict__ Vt,
                                                u16* __restrict__ O) {
  __shared__ u16 Ks[2][128 * 128];
  __shared__ u16 Vs[2][128 * 128];
  __shared__ u16 Ps[4][16 * 128];  // 144 KiB total -> 1 block/CU
  const int tid = threadIdx.x, lane = tid & 63, w = tid >> 6;
  const int lr = lane & 15, lk = lane >> 4;
  const int bh = blockIdx.x, b = bh >> 4, h = bh & 15;
  const int p = blockIdx.y;

  const char* kbase = (const char*)(K + ((size_t)b * 2048) * 2048 + h * 128);
  const char* vbase = (const char*)(Vt + (size_t)bh * 128 * 2048);
  const int bo0 = tid * 16;
  u16* pw = Ps[w];

#define STAGE(KT, BUF)                                                              \
  {                                                                                 \
    const int kv0s = (KT)*128;                                                      \
    _Pragma("unroll") for (int i = 0; i < 8; ++i) {                                 \
      int bo = i * 4096 + bo0;                                                      \
      int r = bo >> 8, cb = bo & 255;                                               \
      async16((char*)Ks[BUF] + i * 4096 + w * 1024,                                 \
              kbase + (size_t)(kv0s + r) * 4096 + (cb ^ ((r & 7) << 4)));           \
    }                                                                               \
    _Pragma("unroll") for (int i = 0; i < 8; ++i) {                                 \
      int bo = i * 4096 + bo0;                                                      \
      int d = bo >> 8, cb = bo & 255;                                               \
      async16((char*)Vs[BUF] + i * 4096 + w * 1024,                                 \
              vbase + (size_t)d * 4096 + (size_t)kv0s * 2 + (cb ^ ((d & 7) << 4))); \
    }                                                                               \
  }

  for (int qi = 0; qi < 2; ++qi) {
    const int qt = qi ? (31 - p) : p;
    const int qw = qt * 64 + w * 16;
    const int nt = (qt >> 1) + 1;
    const int nlim = (qt & 1) ? 8 : 4;  // live n-frags on the diagonal tile

    short8 aq[4];  // Q rows in registers (A-frag: row=lane&15, k=(lane>>4)*8+j)
    const u16* qptr = Q + ((size_t)(b * 2048 + qw + lr)) * 2048 + h * 128;
#pragma unroll
    for (int kk = 0; kk < 4; ++kk) aq[kk] = *(const short8*)(qptr + kk * 32 + lk * 8);

    float mrow[4], lrow[4];
    f32x4 o[8];
#pragma unroll
    for (int r = 0; r < 4; ++r) { mrow[r] = -__builtin_inff(); lrow[r] = 0.f; }
#pragma unroll
    for (int nd = 0; nd < 8; ++nd) o[nd] = (f32x4){0.f, 0.f, 0.f, 0.f};

    // prologue: all waves past previous sweep's compute, then stage tile 0
    __builtin_amdgcn_s_barrier();
    STAGE(0, 0);

    for (int kt = 0; kt < nt; ++kt) {
      const int cur = kt & 1;
      const int kv0 = kt * 128;
      const bool diag = (kt == nt - 1);

      __builtin_amdgcn_s_barrier();  // all waves done compute(kt-1): buf[cur^1] free
      if (kt + 1 < nt) {
        STAGE(kt + 1, cur ^ 1);
        asm volatile("s_waitcnt vmcnt(16)" ::: "memory");  // tile kt done; kt+1 flying
      } else {
        asm volatile("s_waitcnt vmcnt(0)" ::: "memory");
      }
      __builtin_amdgcn_s_barrier();        // tile kt visible to all waves
      __builtin_amdgcn_sched_barrier(0);   // no hoisting of ds_read/MFMA above waits

      const u16* Kc = Ks[cur];
      const u16* Vc = Vs[cur];

      f32x4 s[8];
#pragma unroll
      for (int n = 0; n < 8; ++n) {
        s[n] = (f32x4){-__builtin_inff(), -__builtin_inff(), -__builtin_inff(),
                       -__builtin_inff()};
        if (!diag || n < nlim) {
          f32x4 t = (f32x4){0.f, 0.f, 0.f, 0.f};
#pragma unroll
          for (int kk = 0; kk < 4; ++kk) {
            int row = n * 16 + lr;
            int cb = kk * 64 + lk * 16;
            short8 bk =
                *(const short8*)((const char*)Kc + row * 256 + (cb ^ ((row & 7) << 4)));
            t = __builtin_amdgcn_mfma_f32_16x16x32_bf16(aq[kk], bk, t, 0, 0, 0);
          }
          s[n] = t;
        }
      }
      if (diag) {  // causal mask within live frags
#pragma unroll
        for (int n = 0; n < 8; ++n)
#pragma unroll
          for (int r = 0; r < 4; ++r) {
            int col = kv0 + n * 16 + lr;
            int row = qw + lk * 4 + r;
            if (col > row) s[n][r] = -__builtin_inff();
          }
      }
      float al[4];
#pragma unroll
      for (int r = 0; r < 4; ++r) {
        float mx = s[0][r];
#pragma unroll
        for (int n = 1; n < 8; ++n) mx = fmaxf(mx, s[n][r]);
        mx = fmaxf(mx, __shfl_xor(mx, 1, 64));
        mx = fmaxf(mx, __shfl_xor(mx, 2, 64));
        mx = fmaxf(mx, __shfl_xor(mx, 4, 64));
        mx = fmaxf(mx, __shfl_xor(mx, 8, 64));
        float mn = fmaxf(mrow[r], mx);
        al[r] = exp2f(mrow[r] - mn);
        mrow[r] = mn;
      }
      float rs[4] = {0.f, 0.f, 0.f, 0.f};
#pragma unroll
      for (int n = 0; n < 8; ++n)
#pragma unroll
        for (int r = 0; r < 4; ++r) {
          float pv = exp2f(s[n][r] - mrow[r]);
          s[n][r] = pv;
          rs[r] += pv;
        }
#pragma unroll
      for (int r = 0; r < 4; ++r) {
        float t = rs[r];
        t += __shfl_xor(t, 1, 64); t += __shfl_xor(t, 2, 64);
        t += __shfl_xor(t, 4, 64); t += __shfl_xor(t, 8, 64);
        lrow[r] = lrow[r] * al[r] + t;
      }
#pragma unroll
      for (int nd = 0; nd < 8; ++nd)
#pragma unroll
        for (int r = 0; r < 4; ++r) o[nd][r] *= al[r];

      // P -> per-wave LDS (D-layout write, A-layout read; XOR swizzle both sides)
#pragma unroll
      for (int n = 0; n < 8; ++n)
#pragma unroll
        for (int r = 0; r < 4; ++r) {
          int prow = lk * 4 + r;
          pw[prow * 128 + ((n * 16 + lr) ^ ((prow & 7) << 3))] = f2bf(s[n][r]);
        }

#pragma unroll
      for (int kk = 0; kk < 4; ++kk) {
        short8 pa =
            *(const short8*)(pw + lr * 128 + ((kk * 32 + lk * 8) ^ ((lr & 7) << 3)));
#pragma unroll
        for (int nd = 0; nd < 8; ++nd) {
          int dr = nd * 16 + lr;
          int cb = kk * 64 + lk * 16;
          short8 bv =
              *(const short8*)((const char*)Vc + dr * 256 + (cb ^ ((dr & 7) << 4)));
          o[nd] = __builtin_amdgcn_mfma_f32_16x16x32_bf16(pa, bv, o[nd], 0, 0, 0);
        }
      }
    }

    u16* op = O + ((size_t)(b * 2048 + qw + lk * 4)) * 2048 + h * 128;
#pragma unroll
    for (int r = 0; r < 4; ++r) {
      float inv = 1.0f / lrow[r];
#pragma unroll
      for (int nd = 0; nd < 8; ++nd)
        op[(size_t)r * 2048 + nd * 16 + lr] = f2bf(o[nd][r] * inv);
    }
  }
#undef STAGE
}

extern "C" void kernel_launch(void* const* d_in, const int* in_sizes, int n_in,
                              void* d_out, int out_size, void* d_ws, size_t ws_size,
                              hipStream_t stream) {
  const float* x = (const float*)d_in[0];
  const float* cosb = (const float*)d_in[1];
  const float* sinb = (const float*)d_in[2];
  const float* Wq = (const float*)d_in[3];
  const float* Wk = (const float*)d_in[4];
  const float* Wv = (const float*)d_in[5];
  const float* Wo = (const float*)d_in[6];
  float* out = (float*)d_out;
  char* ws = (char*)d_ws;

  const size_t XB = (size_t)4096 * 2048 * 2;  // 16 MiB (bf16 activations)
  const size_t WB = (size_t)2048 * 2048 * 2;  // 8 MiB (bf16 weights)
  u16* xb  = (u16*)(ws);
  u16* wqb = (u16*)(ws + XB);
  u16* wkb = (u16*)(ws + XB + WB);
  u16* wvb = (u16*)(ws + XB + 2 * WB);
  u16* wob = (u16*)(ws + XB + 3 * WB);
  u16* qb  = (u16*)(ws + XB + 4 * WB);
  u16* kb  = (u16*)(ws + XB + 4 * WB + XB);
  u16* vb  = (u16*)(ws + XB + 4 * WB + 2 * XB);
  u16* vtb = (u16*)(ws + XB + 4 * WB + 3 * XB);
  u16* ob  = (u16*)(ws + XB + 4 * WB + 4 * XB);  // total 128 MiB

  cvt_bf16<<<4096, 256, 0, stream>>>(x, xb, 8388608);
  cvt_bf16<<<2048, 256, 0, stream>>>(Wq, wqb, 4194304);
  cvt_bf16<<<2048, 256, 0, stream>>>(Wk, wkb, 4194304);
  cvt_bf16<<<2048, 256, 0, stream>>>(Wv, wvb, 4194304);
  cvt_bf16<<<2048, 256, 0, stream>>>(Wo, wob, 4194304);
  gemm_qkv<<<dim3(16, 32, 3), 256, 0, stream>>>(xb, wqb, wkb, wvb, qb, kb, vb);
  rmsrope<<<32768, 256, 0, stream>>>(qb, kb, cosb, sinb);
  transpose_v<<<dim3(32, 2, 32), 256, 0, stream>>>(vb, vtb);
  attn_fwd<<<dim3(32, 16), 256, 0, stream>>>(qb, kb, vtb, ob);
  gemm_out<<<dim3(16, 32), 256, 0, stream>>>(ob, wob, out);
}